// Round 2
// baseline (466.656 us; speedup 1.0000x reference)
//
#include <hip/hip_runtime.h>
#include <hip/hip_cooperative_groups.h>

namespace cg = cooperative_groups;

#define C_COLS 16
#define NT 256
#define NB 1024  // 4 blocks/CU x 256 CU; co-residency guaranteed by __launch_bounds__(256,4)

typedef float floatx4 __attribute__((ext_vector_type(4)));  // native vec for nontemporal builtin

// ---------------------------------------------------------------------------
// Single fused cooperative kernel:
//   phase 1: grid-stride NaN-masked reduce -> per-block partials in ws
//   grid.sync()
//   phase 2: block 0 reduces partials -> mean[16]   (same summation tree as
//            the previous k_reduce/k_final pair -> bit-identical result)
//   grid.sync()
//   phase 3: grid-stride fill, nontemporal stores (don't evict x from L3)
// ---------------------------------------------------------------------------
__global__ __launch_bounds__(NT, 4) void k_fused(const float4* __restrict__ x4,
                                                 float4* __restrict__ o4,
                                                 long long n4, long long n,
                                                 float* __restrict__ ws) {
    const int tid = threadIdx.x;
    const long long gid = (long long)blockIdx.x * NT + tid;
    const long long stride = (long long)gridDim.x * NT;  // % 4 == 0 (NT=256)

    // ---- phase 1: reduce ----
    float s0 = 0.f, s1 = 0.f, s2 = 0.f, s3 = 0.f;
    float c0 = 0.f, c1 = 0.f, c2 = 0.f, c3 = 0.f;

    #pragma unroll 4
    for (long long i = gid; i < n4; i += stride) {
        float4 v = x4[i];
        bool m0 = (v.x == v.x); s0 += m0 ? v.x : 0.f; c0 += m0 ? 1.f : 0.f;
        bool m1 = (v.y == v.y); s1 += m1 ? v.y : 0.f; c1 += m1 ? 1.f : 0.f;
        bool m2 = (v.z == v.z); s2 += m2 ? v.z : 0.f; c2 += m2 ? 1.f : 0.f;
        bool m3 = (v.w == v.w); s3 += m3 ? v.w : 0.f; c3 += m3 ? 1.f : 0.f;
    }

    // Butterfly over lanes with identical (lane & 3): xor offsets 4,8,16,32.
    for (int off = 4; off < 64; off <<= 1) {
        s0 += __shfl_xor(s0, off, 64);
        s1 += __shfl_xor(s1, off, 64);
        s2 += __shfl_xor(s2, off, 64);
        s3 += __shfl_xor(s3, off, 64);
        c0 += __shfl_xor(c0, off, 64);
        c1 += __shfl_xor(c1, off, 64);
        c2 += __shfl_xor(c2, off, 64);
        c3 += __shfl_xor(c3, off, 64);
    }

    __shared__ float bsum[C_COLS];
    __shared__ float bcnt[C_COLS];
    if (tid < C_COLS) { bsum[tid] = 0.f; bcnt[tid] = 0.f; }
    __syncthreads();

    if ((tid & 63) < 4) {  // lanes 0..3 of each wave hold group totals
        const int cb4 = (tid & 3) * 4;
        atomicAdd(&bsum[cb4 + 0], s0);
        atomicAdd(&bsum[cb4 + 1], s1);
        atomicAdd(&bsum[cb4 + 2], s2);
        atomicAdd(&bsum[cb4 + 3], s3);
        atomicAdd(&bcnt[cb4 + 0], c0);
        atomicAdd(&bcnt[cb4 + 1], c1);
        atomicAdd(&bcnt[cb4 + 2], c2);
        atomicAdd(&bcnt[cb4 + 3], c3);
    }
    __syncthreads();

    if (tid < C_COLS) {
        ws[(long long)blockIdx.x * 32 + tid] = bsum[tid];
        ws[(long long)blockIdx.x * 32 + C_COLS + tid] = bcnt[tid];
    }
    __threadfence();  // device-scope release of partials (cross-XCD visibility)

    cg::this_grid().sync();

    // ---- phase 2: final reduce (block 0 only, deterministic order) ----
    float* mean = ws + (long long)gridDim.x * 32;
    if (blockIdx.x == 0) {
        const int c = tid & 15;
        const int r0 = tid >> 4;  // 0..15
        float S = 0.f, Cn = 0.f;
        for (int p = r0; p < (int)gridDim.x; p += 16) {
            S  += ws[(long long)p * 32 + c];
            Cn += ws[(long long)p * 32 + 16 + c];
        }
        __shared__ float ssum[NT];
        __shared__ float scnt[NT];
        ssum[tid] = S;
        scnt[tid] = Cn;
        __syncthreads();
        if (tid < 16) {
            float SS = 0.f, CC = 0.f;
            for (int r = 0; r < 16; ++r) {
                SS += ssum[r * 16 + tid];
                CC += scnt[r * 16 + tid];
            }
            // scalar tail (elements n4*4 .. n-1) — unused for this shape
            const float* x = (const float*)x4;
            for (long long j = n4 * 4; j < n; ++j) {
                if ((int)(j % 16) == tid) {
                    float v = x[j];
                    if (v == v) { SS += v; CC += 1.f; }
                }
            }
            mean[tid] = SS / fmaxf(CC, 1.f);
        }
        __threadfence();  // release mean
    }

    cg::this_grid().sync();

    // ---- phase 3: fill ----
    const int cb = (int)(gid & 3) * 4;  // constant per thread (stride % 4 == 0)
    const float m0 = mean[cb + 0];
    const float m1 = mean[cb + 1];
    const float m2 = mean[cb + 2];
    const float m3 = mean[cb + 3];

    #pragma unroll 4
    for (long long i = gid; i < n4; i += stride) {
        float4 v = x4[i];
        v.x = (v.x == v.x) ? v.x : m0;
        v.y = (v.y == v.y) ? v.y : m1;
        v.z = (v.z == v.z) ? v.z : m2;
        v.w = (v.w == v.w) ? v.w : m3;
        floatx4 nv;
        nv.x = v.x; nv.y = v.y; nv.z = v.z; nv.w = v.w;
        __builtin_nontemporal_store(nv, (floatx4*)&o4[i]);
    }

    if (gid == 0) {  // scalar tail (unused for this shape)
        const float* x = (const float*)x4;
        float* o = (float*)o4;
        for (long long j = n4 * 4; j < n; ++j) {
            float v = x[j];
            o[j] = (v == v) ? v : mean[(int)(j % 16)];
        }
    }
}

extern "C" void kernel_launch(void* const* d_in, const int* in_sizes, int n_in,
                              void* d_out, int out_size, void* d_ws, size_t ws_size,
                              hipStream_t stream) {
    const float* x = (const float*)d_in[0];
    float* out = (float*)d_out;
    const long long n = (long long)in_sizes[0];
    const long long n4 = n / 4;

    // ws layout: [nb * 32] partial sums/counts, then [16] means.
    int nb = NB;
    {
        long long cap = ((long long)(ws_size / 4) - 16) / 32;
        if (cap < 1) cap = 1;
        if (nb > cap) nb = (int)cap;
    }

    const float4* x4 = (const float4*)x;
    float4* o4 = (float4*)out;
    float* ws = (float*)d_ws;
    long long n4v = n4, nv = n;

    void* args[] = { (void*)&x4, (void*)&o4, (void*)&n4v, (void*)&nv, (void*)&ws };
    (void)hipLaunchCooperativeKernel((const void*)k_fused, dim3(nb), dim3(NT), args, 0, stream);
}

// Round 3
// 244.687 us; speedup vs baseline: 1.9072x; 1.9072x over previous
//
#include <hip/hip_runtime.h>

#define C_COLS 16
#define NT 256
#define NB1 1024   // reduce grid (must match partials layout; summation tree depends on it)
#define NB2 2048   // fill grid

typedef float floatx4 __attribute__((ext_vector_type(4)));  // native vec for nontemporal builtin

// ---------------------------------------------------------------------------
// Kernel 1: grid-stride NaN-masked reduce -> per-block partials.
// 4-deep manual load batching (loads issued before accumulation) for memory-
// level parallelism; accumulation order per thread is IDENTICAL to the
// original single-load loop (increasing i), so results are bit-identical.
// ---------------------------------------------------------------------------
__global__ __launch_bounds__(NT) void k_reduce(const float4* __restrict__ x4,
                                               long long n4,
                                               float* __restrict__ partials) {
    const int tid = threadIdx.x;
    const long long gid = (long long)blockIdx.x * NT + tid;
    const long long stride = (long long)gridDim.x * NT;  // % 4 == 0

    float s0 = 0.f, s1 = 0.f, s2 = 0.f, s3 = 0.f;
    float c0 = 0.f, c1 = 0.f, c2 = 0.f, c3 = 0.f;

#define ACC(v)                                                              \
    do {                                                                    \
        bool m0 = ((v).x == (v).x); s0 += m0 ? (v).x : 0.f; c0 += m0 ? 1.f : 0.f; \
        bool m1 = ((v).y == (v).y); s1 += m1 ? (v).y : 0.f; c1 += m1 ? 1.f : 0.f; \
        bool m2 = ((v).z == (v).z); s2 += m2 ? (v).z : 0.f; c2 += m2 ? 1.f : 0.f; \
        bool m3 = ((v).w == (v).w); s3 += m3 ? (v).w : 0.f; c3 += m3 ? 1.f : 0.f; \
    } while (0)

    long long i = gid;
    for (; i + 3 * stride < n4; i += 4 * stride) {
        float4 va = x4[i];
        float4 vb = x4[i + stride];
        float4 vc = x4[i + 2 * stride];
        float4 vd = x4[i + 3 * stride];
        ACC(va); ACC(vb); ACC(vc); ACC(vd);
    }
    for (; i < n4; i += stride) {
        float4 v = x4[i];
        ACC(v);
    }
#undef ACC

    // Butterfly over lanes with identical (lane & 3): xor offsets 4,8,16,32.
    for (int off = 4; off < 64; off <<= 1) {
        s0 += __shfl_xor(s0, off, 64);
        s1 += __shfl_xor(s1, off, 64);
        s2 += __shfl_xor(s2, off, 64);
        s3 += __shfl_xor(s3, off, 64);
        c0 += __shfl_xor(c0, off, 64);
        c1 += __shfl_xor(c1, off, 64);
        c2 += __shfl_xor(c2, off, 64);
        c3 += __shfl_xor(c3, off, 64);
    }

    __shared__ float bsum[C_COLS];
    __shared__ float bcnt[C_COLS];
    if (tid < C_COLS) { bsum[tid] = 0.f; bcnt[tid] = 0.f; }
    __syncthreads();

    if ((tid & 63) < 4) {  // lanes 0..3 of each wave hold group totals
        const int cb4 = (tid & 3) * 4;
        atomicAdd(&bsum[cb4 + 0], s0);
        atomicAdd(&bsum[cb4 + 1], s1);
        atomicAdd(&bsum[cb4 + 2], s2);
        atomicAdd(&bsum[cb4 + 3], s3);
        atomicAdd(&bcnt[cb4 + 0], c0);
        atomicAdd(&bcnt[cb4 + 1], c1);
        atomicAdd(&bcnt[cb4 + 2], c2);
        atomicAdd(&bcnt[cb4 + 3], c3);
    }
    __syncthreads();

    if (tid < C_COLS) {
        partials[(long long)blockIdx.x * 32 + tid] = bsum[tid];
        partials[(long long)blockIdx.x * 32 + C_COLS + tid] = bcnt[tid];
    }
}

// ---------------------------------------------------------------------------
// Kernel 2: fill, with the final reduce done redundantly per block (identical
// summation tree to the old single-block k_final -> bit-identical mean,
// ~128 KB L3-broadcast read per block). Removes the middle kernel and its
// full-GPU drain. Output uses nontemporal stores so the 128 MB write stream
// does not evict x from L3 (proven: round-2 FETCH_SIZE showed 100% L3 hit
// on the re-read).
// ---------------------------------------------------------------------------
__global__ __launch_bounds__(NT) void k_fill(const float4* __restrict__ x4,
                                             float4* __restrict__ o4,
                                             long long n4, long long n,
                                             const float* __restrict__ partials,
                                             int nb1) {
    const int tid = threadIdx.x;
    const long long gid = (long long)blockIdx.x * NT + tid;
    const long long stride = (long long)gridDim.x * NT;  // % 4 == 0

    // ---- phase A: per-block final reduce (same tree as old k_final) ----
    __shared__ float ssum[NT];
    __shared__ float scnt[NT];
    __shared__ float smean[C_COLS];
    {
        const int c = tid & 15;
        const int r0 = tid >> 4;  // 0..15
        float S = 0.f, Cn = 0.f;
        #pragma unroll 8
        for (int p = r0; p < nb1; p += 16) {
            S  += partials[(long long)p * 32 + c];
            Cn += partials[(long long)p * 32 + 16 + c];
        }
        ssum[tid] = S;
        scnt[tid] = Cn;
        __syncthreads();
        if (tid < 16) {
            float SS = 0.f, CC = 0.f;
            for (int r = 0; r < 16; ++r) {
                SS += ssum[r * 16 + tid];
                CC += scnt[r * 16 + tid];
            }
            // scalar tail (elements n4*4 .. n-1) — unused for this shape
            const float* x = (const float*)x4;
            for (long long j = n4 * 4; j < n; ++j) {
                if ((int)(j % 16) == tid) {
                    float v = x[j];
                    if (v == v) { SS += v; CC += 1.f; }
                }
            }
            smean[tid] = SS / fmaxf(CC, 1.f);
        }
        __syncthreads();
    }

    // ---- phase B: fill ----
    const int cb = (int)(gid & 3) * 4;  // constant per thread (stride % 4 == 0)
    const float m0 = smean[cb + 0];
    const float m1 = smean[cb + 1];
    const float m2 = smean[cb + 2];
    const float m3 = smean[cb + 3];

    #pragma unroll 4
    for (long long i = gid; i < n4; i += stride) {
        float4 v = x4[i];
        floatx4 nv;
        nv.x = (v.x == v.x) ? v.x : m0;
        nv.y = (v.y == v.y) ? v.y : m1;
        nv.z = (v.z == v.z) ? v.z : m2;
        nv.w = (v.w == v.w) ? v.w : m3;
        __builtin_nontemporal_store(nv, (floatx4*)&o4[i]);
    }

    if (gid == 0) {  // scalar tail (unused for this shape)
        const float* x = (const float*)x4;
        float* o = (float*)o4;
        for (long long j = n4 * 4; j < n; ++j) {
            float v = x[j];
            o[j] = (v == v) ? v : smean[(int)(j % 16)];
        }
    }
}

extern "C" void kernel_launch(void* const* d_in, const int* in_sizes, int n_in,
                              void* d_out, int out_size, void* d_ws, size_t ws_size,
                              hipStream_t stream) {
    const float* x = (const float*)d_in[0];
    float* out = (float*)d_out;
    const long long n = (long long)in_sizes[0];
    const long long n4 = n / 4;

    // ws layout: [nb1 * 32] partial sums/counts.
    int nb1 = NB1;
    {
        long long cap = (long long)(ws_size / 4) / 32;
        if (cap < 1) cap = 1;
        if (nb1 > cap) nb1 = (int)cap;
    }
    float* partials = (float*)d_ws;

    k_reduce<<<nb1, NT, 0, stream>>>((const float4*)x, n4, partials);
    k_fill<<<NB2, NT, 0, stream>>>((const float4*)x, (float4*)out, n4, n,
                                   partials, nb1);
}